// Round 9
// baseline (369.981 us; speedup 1.0000x reference)
//
#include <hip/hip_runtime.h>

// ---------------------------------------------------------------------------
// Earth padding of 5 strips (B=1, C=256) + edge-row cross-strip convs.
// Outputs (concatenated): (256,34,364)(256,64,724)(256,184,1444)(256,64,724)(256,34,364)
//
// Round-9: conv weight-traffic attack. Round-8 analysis: conv ~180us because
// 1080 blocks x 1.25MB weight table = 1.35GB of L2/L3 traffic, 8 jobs x 1.25MB
// working set thrashing each 4MB XCD-L2, and no prefetch (latency exposed
// every 4-ic chunk). Now:
//   - both-rows blocks (rows share all weights): 90 blocks/job, grid 720
//   - job = blockIdx.x & 7  -> each XCD streams ONE job's table from its L2
//   - wv/wn float4 ping-pong prefetch, __launch_bounds__(256,2) (256-VGPR cap)
//   k1 transpose_all : float4 weight tables [(ic/4)][k][oc][ic%4]
//   k2 conv_kernel   : 720 blocks (8 jobs x 90 tiles), both rows per block
//   k3 copy_kernel   : unchanged (measured ~HBM ceiling)
// ---------------------------------------------------------------------------

struct ConvJob {
  const float* x; const float* wt; const float* bias; float* out;
  int Hin, Win, r0, Hout, Wcore, h0;
};
struct ConvParams { ConvJob j[8]; };

struct CopyParams {
  const float* in0; const float* in1; const float* in2; const float* in3; const float* in4;
  float* o0; float* o1; float* o2; float* o3; float* o4;
};

struct WTParams { const float* src[4]; float* dst[4]; };

// --- weight transpose: dst[((ic/4)*5 + k)*1024 + oc*4 + (ic%4)] ---
// which 0,1: src is wi [ic][oc][1][k] ; which 2,3: src is wo [oc][ic][1][k]
__global__ __launch_bounds__(256) void transpose_all_kernel(WTParams p) {
  int b = blockIdx.x;                       // 5120 blocks = 4 * 1280
  int which = b / 1280;
  int idx = (b - which * 1280) * 256 + threadIdx.x;   // 0..327679
  int hi = idx >> 10;                       // icq*5 + k
  int icq = hi / 5;
  int k = hi - icq * 5;
  int lo = idx & 1023;
  int oc = lo >> 2;
  int icr = lo & 3;
  int ic = icq * 4 + icr;
  const float* s = p.src[which];
  float v = (which < 2) ? s[(ic * 256 + oc) * 5 + k] : s[(oc * 256 + ic) * 5 + k];
  p.dst[which][idx] = v;
}

// ---------------------------------------------------------------------------
// Conv kernel. TR=true: circular transposed conv (k = i+4-2cc);
// TR=false: circular fwd conv (k = cc-2i). Both rows of the tile per block.
// ---------------------------------------------------------------------------

// coalesced epilogue for one row: acc -> LDS transpose -> float2 stores
template <int NOUT>
__device__ __forceinline__ void epilogue_row(const ConvJob& jb, int g0, int t, int r,
                                             const float* acc, float* xs) {
  __syncthreads();
#pragma unroll
  for (int i = 0; i < NOUT; ++i) xs[i * 257 + t] = acc[i];
  __syncthreads();
  constexpr int SL = NOUT / 2;              // float2 slots per oc-row
  constexpr int OCR = 256 / SL;             // oc-rows per round
  const int Hout = jb.Hout;
  const int Wop = jb.Wcore + 4;
#pragma unroll
  for (int q = 0; q < SL; ++q) {
    int oc = (t / SL) + q * OCR;
    int s = t & (SL - 1);
    float2 v = make_float2(xs[(2 * s) * 257 + oc], xs[(2 * s + 1) * 257 + oc]);
    *(float2*)(jb.out + ((size_t)(oc * Hout + jb.h0 + r)) * Wop + 2 + g0 + 2 * s) = v;
  }
  // wrap-edge duplication (first/last tile only), thread t = oc
  float* orow = jb.out + ((size_t)(t * Hout + jb.h0 + r)) * Wop;
  if (g0 == 0) {
    orow[jb.Wcore + 2] = xs[0 * 257 + t];
    orow[jb.Wcore + 3] = xs[1 * 257 + t];
  }
  if (g0 + NOUT == jb.Wcore) {
    orow[0] = xs[(NOUT - 2) * 257 + t];
    orow[1] = xs[(NOUT - 1) * 257 + t];
  }
}

template <int NOUT, int NCC, bool TR>
__device__ __forceinline__ void conv2(const ConvJob jb, int tile, int t, float* xs,
                                      float bv) {
  const int Win = jb.Win;
  int g0 = tile * NOUT;
  int base0 = TR ? (g0 >> 1) - 1 : 2 * g0 - 2;

  // stage X columns for both rows: xs[(r*NCC+cc)*256 + ic], thread t = ic
#pragma unroll
  for (int r = 0; r < 2; ++r) {
    const float* xrow = jb.x + ((size_t)(t * jb.Hin + jb.r0 + r)) * Win;
#pragma unroll
    for (int cc = 0; cc < NCC; ++cc) {
      int col = base0 + cc;
      col += (col < 0) ? Win : 0;
      col -= (col >= Win) ? Win : 0;
      xs[(r * NCC + cc) * 256 + t] = xrow[col];
    }
  }
  __syncthreads();

  float a0[NOUT], a1[NOUT];
#pragma unroll
  for (int i = 0; i < NOUT; ++i) { a0[i] = bv; a1[i] = bv; }

  const float* wq = jb.wt + t * 4;          // thread t = oc
  float4 wv[5], wn[5];
#pragma unroll
  for (int k = 0; k < 5; ++k) wv[k] = *(const float4*)(wq + (size_t)k * 1024);

#pragma unroll 1
  for (int icq = 0; icq < 64; ++icq) {
    if (icq < 63) {
#pragma unroll
      for (int k = 0; k < 5; ++k)
        wn[k] = *(const float4*)(wq + (size_t)((icq + 1) * 5 + k) * 1024);
    }
    int ic0 = icq * 4;
#pragma unroll
    for (int cc = 0; cc < NCC; ++cc) {
      float4 x0 = *(const float4*)&xs[cc * 256 + ic0];
      float4 x1 = *(const float4*)&xs[(NCC + cc) * 256 + ic0];
#pragma unroll
      for (int i = 0; i < NOUT; ++i) {
        int k = TR ? (i + 4 - 2 * cc) : (cc - 2 * i);
        if (k >= 0 && k < 5) {
          float4 w = wv[k];
          a0[i] += w.x * x0.x + w.y * x0.y + w.z * x0.z + w.w * x0.w;
          a1[i] += w.x * x1.x + w.y * x1.y + w.z * x1.z + w.w * x1.w;
        }
      }
    }
    if (icq < 63) {
#pragma unroll
      for (int k = 0; k < 5; ++k) wv[k] = wn[k];
    }
  }

  epilogue_row<NOUT>(jb, g0, t, 0, a0, xs);
  __syncthreads();
  epilogue_row<NOUT>(jb, g0, t, 1, a1, xs);
}

// grid = 720: job = bx & 7 (XCD-pinned), tile = bx >> 3 (90 tiles per job)
__global__ __launch_bounds__(256, 2) void conv_kernel(ConvParams p) {
  __shared__ float xs[2 * 19 * 256];        // 38 KB (max NCC=19, both rows)
  int bx = blockIdx.x;
  int t = threadIdx.x;
  int job = bx & 7;
  int tile = bx >> 3;
  const ConvJob jb = p.j[job];
  switch (job >> 1) {
    case 0: conv2<16, 10, true>(jb, tile, t, xs, 0.f); break;          // j0,j1: convT 1440
    case 1: conv2<8, 6, true>(jb, tile, t, xs, 0.f); break;            // j2,j3: convT 720
    case 2: conv2<8, 19, false>(jb, tile, t, xs, jb.bias[t]); break;   // j4,j5: fwd 720
    default: conv2<4, 11, false>(jb, tile, t, xs, jb.bias[t]); break;  // j6,j7: fwd 360
  }
}

// ---------------------------------------------------------------------------
// Copy kernel (unchanged — measured near HBM ceiling)
// ---------------------------------------------------------------------------

__device__ __forceinline__ float4 pack4(float2 a, float2 b) {
  return make_float4(a.x, a.y, b.x, b.y);
}

template <int H, int W>
__device__ __forceinline__ void copy_row(const float* __restrict__ in,
                                         float* __restrict__ out, int rl, int lane) {
  constexpr int CORE = W / 4;               // interior float4 columns: 1..CORE-1
  int c = rl / H;
  const float* src = in + (size_t)rl * W;
  float* dst = out + (size_t)(rl + c * 4 + 2) * (W + 4);
  int w4 = 1 + lane;
  while (w4 < CORE) {
    int w4b = w4 + 64;
    float2 a0 = *(const float2*)(src + w4 * 4 - 2);
    float2 b0 = *(const float2*)(src + w4 * 4);
    if (w4b < CORE) {
      float2 a1 = *(const float2*)(src + w4b * 4 - 2);
      float2 b1 = *(const float2*)(src + w4b * 4);
      *(float4*)(dst + w4 * 4) = pack4(a0, b0);
      *(float4*)(dst + w4b * 4) = pack4(a1, b1);
    } else {
      *(float4*)(dst + w4 * 4) = pack4(a0, b0);
    }
    w4 += 128;
  }
  if (lane == 0) {
    // dst[0..3] == dst[W..W+3] == {x[W-2], x[W-1], x[0], x[1]}
    float2 E = *(const float2*)(src + W - 2);
    float2 F = *(const float2*)(src);
    float4 v = pack4(E, F);
    *(float4*)(dst) = v;
    *(float4*)(dst + W) = v;
  }
}

__device__ __forceinline__ void zero_row(const CopyParams& p, int z, int lane) {
  int strip = z >> 9, cr = z & 511, c = cr >> 1, r = cr & 1;
  float* dst = strip ? p.o4 + (size_t)(c * 34 + 32 + r) * 364
                     : p.o0 + (size_t)(c * 34 + r) * 364;
  for (int w4 = lane; w4 < 91; w4 += 64)
    *(float4*)(dst + w4 * 4) = make_float4(0.f, 0.f, 0.f, 0.f);
}

// row-job space: [0,46080) s2 | [,61440) s1 | [,76800) s3 | [,84480) s0
//                | [,92160) s4 | [,93184) zero rows
__device__ __forceinline__ void do_row(const CopyParams& p, int gid, int lane) {
  if (gid < 46080)      copy_row<180, 1440>(p.in2, p.o2, gid, lane);
  else if (gid < 61440) copy_row<60, 720>(p.in1, p.o1, gid - 46080, lane);
  else if (gid < 76800) copy_row<60, 720>(p.in3, p.o3, gid - 61440, lane);
  else if (gid < 84480) copy_row<30, 360>(p.in0, p.o0, gid - 76800, lane);
  else if (gid < 92160) copy_row<30, 360>(p.in4, p.o4, gid - 84480, lane);
  else                  zero_row(p, gid - 92160, lane);
}

__global__ __launch_bounds__(256, 8) void copy_kernel(CopyParams p) {
  int wid = blockIdx.x * 4 + (threadIdx.x >> 6);   // 8192 waves
  int lane = threadIdx.x & 63;
  for (int gid = wid; gid < 93184; gid += 8192) do_row(p, gid, lane);
}

extern "C" void kernel_launch(void* const* d_in, const int* in_sizes, int n_in,
                              void* d_out, int out_size, void* d_ws, size_t ws_size,
                              hipStream_t stream) {
  const float* s0 = (const float*)d_in[0];   // (256,30,360)
  const float* s1 = (const float*)d_in[1];   // (256,60,720)
  const float* s2 = (const float*)d_in[2];   // (256,180,1440)
  const float* s3 = (const float*)d_in[3];   // (256,60,720)
  const float* s4 = (const float*)d_in[4];   // (256,30,360)
  const float* wi0 = (const float*)d_in[5];  // (256,256,1,5) [ic][oc][k]
  const float* wi1 = (const float*)d_in[6];
  const float* wo0 = (const float*)d_in[7];  // (256,256,1,5) [oc][ic][k]
  const float* bo0 = (const float*)d_in[8];
  const float* wo1 = (const float*)d_in[9];
  const float* bo1 = (const float*)d_in[10];

  float* out = (float*)d_out;
  float* out0 = out;                 // (256,34,364)
  float* out1 = out + 3168256;       // (256,64,724)
  float* out2 = out + 15030272;      // (256,184,1444)
  float* out3 = out + 83048448;      // (256,64,724)
  float* out4 = out + 94910464;      // (256,34,364)

  // workspace: 4 float4-layout weight tables [(ic/4)][k][oc][ic%4]
  float* wt0 = (float*)d_ws;
  float* wt1 = wt0 + 327680;
  float* wt2 = wt1 + 327680;
  float* wt3 = wt2 + 327680;

  WTParams wp;
  wp.src[0] = wi0; wp.src[1] = wi1; wp.src[2] = wo0; wp.src[3] = wo1;
  wp.dst[0] = wt0; wp.dst[1] = wt1; wp.dst[2] = wt2; wp.dst[3] = wt3;
  transpose_all_kernel<<<5120, 256, 0, stream>>>(wp);

  ConvParams cp;
  //           x    wt   bias    out   Hin  Win   r0  Hout Wcore h0
  cp.j[0] = {s1, wt0, nullptr, out2,  60,  720,  58, 184, 1440,   0}; // convT -> out2 top
  cp.j[1] = {s3, wt0, nullptr, out2,  60,  720,   0, 184, 1440, 182}; // convT -> out2 bottom
  cp.j[2] = {s0, wt1, nullptr, out1,  30,  360,  28,  64,  720,   0}; // convT -> out1 top
  cp.j[3] = {s4, wt1, nullptr, out3,  30,  360,   0,  64,  720,  62}; // convT -> out3 bottom
  cp.j[4] = {s2, wt2, bo0,     out1, 180, 1440,   0,  64,  720,  62}; // fwd   -> out1 bottom
  cp.j[5] = {s2, wt2, bo0,     out3, 180, 1440, 178,  64,  720,   0}; // fwd   -> out3 top
  cp.j[6] = {s1, wt3, bo1,     out0,  60,  720,   0,  34,  360,  32}; // fwd   -> out0 bottom
  cp.j[7] = {s3, wt3, bo1,     out4,  60,  720,  58,  34,  360,   0}; // fwd   -> out4 top
  conv_kernel<<<720, 256, 0, stream>>>(cp);

  CopyParams kp;
  kp.in0 = s0; kp.in1 = s1; kp.in2 = s2; kp.in3 = s3; kp.in4 = s4;
  kp.o0 = out0; kp.o1 = out1; kp.o2 = out2; kp.o3 = out3; kp.o4 = out4;
  copy_kernel<<<2048, 256, 0, stream>>>(kp);
}